// Round 2
// baseline (469.959 us; speedup 1.0000x reference)
//
#include <hip/hip_runtime.h>
#include <math.h>

// Problem constants (from reference): B=16384, C=72, H=34, IN_CH=12, GROWTH=12, n=5
//   x:      (B, 72, 34, 1)  fp32
//   out:    (B, 84, 34, 1)  fp32  = concat([x, conv(h)], ch axis)
//
// Channel map of xxx (the BN input), derived from the reference's reversed-gate concat:
//   region r = c/12:  scale s[r], source channel src = c + dd[r]
//   dd = {0, +36, +12, -12, -36, 0}   (involution: x regions 1<->4, 2<->3 swap)
//   scales per xxx region: {g1, gates[3], gates[2], gates[1], gates[0], 1}
//   Equivalently, x channel cx feeds xxx channel cx + dd[cx/12] with scale
//   index sidx[cx/12] = {0, 4, 3, 2, 1, 5} (x group g is gated by gates[g]).
//
// BN stats per channel c of xxx: S[c] = sum_b s_b * rowsum_x[b,src], SS[c] = sum_b s_b^2 * rowsumsq_x[b,src]

#define BN_EPS 1e-5f

// ws layout (float offsets)
#define WS_S    0                 // 72: BN sum accumulator (memset to 0 before K1)
#define WS_SS   72                // 72: BN sumsq accumulator
#define WS_A    144               // 72: gamma * rsqrt(var+eps)
#define WS_B    216               // 72: beta - mu*A
#define WS_WT   288               // 72*12*4 = 3456: conv_w transposed to [c][o][4] (k padded to 4)
#define WS_GATE (288 + 3456)      // B*6: per-batch scales {g1, g3, g2, g1, g0, 1}

__device__ __forceinline__ float sigmoidf_(float z) { return 1.f / (1.f + expf(-z)); }

// ---------------------------------------------------------------------------
// K1: per-batch gates + global BN stats.
// 3 batches per iteration per block; x staged to LDS with stride-35 padding
// (35 mod 32 = 3, gcd(3,32)=1 -> conflict-free column reductions).
// ---------------------------------------------------------------------------
__global__ __launch_bounds__(256) void k1_stats(const float* __restrict__ x,
                                                const float* __restrict__ fw,   // fc_w, 34 floats
                                                const float* __restrict__ fb,   // fc_bias, 1 float
                                                float* __restrict__ ws,
                                                int B, int nTrip)
{
    __shared__ float xs[3 * 2520];        // 3 batches x 72 ch x stride 35
    __shared__ float rs_s[3][72];         // per-batch per-channel sum_h x
    __shared__ float rss_s[3][72];        // sum_h x^2
    __shared__ float wsum_s[3][72];       // sum_h x*w[h]
    __shared__ float sc_s[3][8];          // 6 scales per batch (padded)
    __shared__ float Sacc[72], SSacc[72]; // block-local BN accumulators

    const int tid = threadIdx.x;
    if (tid < 72) { Sacc[tid] = 0.f; SSacc[tid] = 0.f; }

    for (int t = blockIdx.x; t < nTrip; t += gridDim.x) {
        const int b0 = t * 3;

        // stage 3 batches (612 float4 each), coalesced global reads
        for (int idx = tid; idx < 3 * 612; idx += 256) {
            int g = idx / 612, v = idx - g * 612;
            int b = b0 + g;
            if (b < B) {
                float4 q = ((const float4*)(x + (size_t)b * 2448))[v];
                float vv[4] = {q.x, q.y, q.z, q.w};
#pragma unroll
                for (int j = 0; j < 4; ++j) {
                    int e = v * 4 + j;
                    int c = e / 34, h = e - c * 34;
                    xs[g * 2520 + c * 35 + h] = vv[j];
                }
            }
        }
        __syncthreads();

        // per-(batch,channel) reductions over H; fw[h] is wave-uniform -> s_load
        if (tid < 216) {
            int g = tid / 72, c = tid - g * 72;
            float rs = 0.f, rss = 0.f, wsm = 0.f;
            if (b0 + g < B) {
                const float* p = &xs[g * 2520 + c * 35];
#pragma unroll
                for (int h = 0; h < 34; ++h) {
                    float v = p[h];
                    rs += v;
                    rss = fmaf(v, v, rss);
                    wsm = fmaf(v, fw[h], wsm);
                }
            }
            rs_s[g][c] = rs; rss_s[g][c] = rss; wsum_s[g][c] = wsm;
        }
        __syncthreads();

        // gates (one thread per batch; trivial work)
        if (tid < 3 && b0 + tid < B) {
            int g = tid;
            float lm[6]; // lm[0]=lin_x11, lm[1..5]=lin_m[0..4]
#pragma unroll
            for (int r = 0; r < 6; ++r) {
                float s = 0.f;
                for (int c = 0; c < 12; ++c) s += wsum_s[g][r * 12 + c];
                lm[r] = s * (1.f / 12.f) + fb[0];
            }
            float lin_out = lm[5];
            float sc[6];
            sc[0] = sigmoidf_(lin_out + lm[0]);  // g1
            sc[1] = sigmoidf_(lm[4] + lin_out);  // gates[3]
            sc[2] = sigmoidf_(lm[3] + lin_out);  // gates[2]
            sc[3] = sigmoidf_(lm[2] + lin_out);  // gates[1]
            sc[4] = sigmoidf_(lm[1] + lin_out);  // gates[0]
            sc[5] = 1.f;
            float* gb = ws + WS_GATE + (size_t)(b0 + g) * 6;
#pragma unroll
            for (int r = 0; r < 6; ++r) { sc_s[g][r] = sc[r]; gb[r] = sc[r]; }
        }
        __syncthreads();

        // accumulate BN stats for the 3 batches (uses src permutation)
        if (tid < 72) {
            const int c = tid;
            const int r = c / 12;
            const int dd[6] = {0, 36, 12, -12, -36, 0};
            const int src = c + dd[r];
            float a = 0.f, q = 0.f;
#pragma unroll
            for (int g = 0; g < 3; ++g) {
                if (b0 + g < B) {
                    float s = sc_s[g][r];
                    a = fmaf(s, rs_s[g][src], a);
                    q = fmaf(s * s, rss_s[g][src], q);
                }
            }
            Sacc[c] += a; SSacc[c] += q;
        }
        __syncthreads(); // protect LDS reuse next iteration
    }

    if (tid < 72) {
        atomicAdd(&ws[WS_S + tid], Sacc[tid]);
        atomicAdd(&ws[WS_SS + tid], SSacc[tid]);
    }
}

// ---------------------------------------------------------------------------
// K2: finalize BN affine (A,B) and transpose conv_w -> [c][o][4] for uniform
// float4 scalar loads in K3.
// ---------------------------------------------------------------------------
__global__ void k2_finalize(const float* __restrict__ gamma,
                            const float* __restrict__ beta,
                            const float* __restrict__ cw,   // (12,72,3) flat
                            float* __restrict__ ws, float invN)
{
    const int tid = threadIdx.x;
    if (tid < 72) {
        float S = ws[WS_S + tid], SS = ws[WS_SS + tid];
        float mu = S * invN;
        float var = SS * invN - mu * mu;
        float inv = rsqrtf(var + BN_EPS);
        float A = gamma[tid] * inv;
        ws[WS_A + tid] = A;
        ws[WS_B + tid] = beta[tid] - mu * A;
    }
    for (int i = tid; i < 12 * 72 * 3; i += 256) {
        int o = i / 216, rem = i - o * 216;
        int c = rem / 3, k = rem - c * 3;
        ws[WS_WT + c * 48 + o * 4 + k] = cw[i]; // [c][o][4], 4th lane unused
    }
}

// ---------------------------------------------------------------------------
// K3: transform + conv + output. 6 batches per block.
// h staged in LDS as [g][cdst][36] with zero halo columns (indices 0 and 35)
// so the conv inner loop is branch-free. THE PERMUTATION: x channel cx feeds
// h channel cdst = cx + dd[cx/12] with gate sidx[cx/12]; A/B are those of cdst.
// Conv weights are read with wave-uniform indices -> scalar loads; h reads are
// stride-1 across lanes -> conflict-free.
// ---------------------------------------------------------------------------
__global__ __launch_bounds__(256) void k3_out(const float* __restrict__ x,
                                              const float* __restrict__ ws,
                                              float* __restrict__ out, int B)
{
    __shared__ float hp[6 * 2592];   // 6 x 72 x 36
    __shared__ float2 AB[72];
    __shared__ float gl[6][8];

    const int tid = threadIdx.x;
    const int b0 = blockIdx.x * 6;
    int nb = B - b0; if (nb > 6) nb = 6;

    if (tid < 72) AB[tid] = make_float2(ws[WS_A + tid], ws[WS_B + tid]);
    for (int t2 = tid; t2 < nb * 6; t2 += 256) {
        int g = t2 / 6, j = t2 - g * 6;
        gl[g][j] = ws[WS_GATE + (size_t)(b0 + g) * 6 + j];
    }
    for (int t2 = tid; t2 < nb * 72; t2 += 256) {
        int g = t2 / 72, c = t2 - g * 72;
        hp[g * 2592 + c * 36] = 0.f;
        hp[g * 2592 + c * 36 + 35] = 0.f;
    }
    __syncthreads();

    // transform: read x (float4), write passthrough out, write h to LDS
    // (channel-permuted destination)
    for (int idx = tid; idx < nb * 612; idx += 256) {
        int g = idx / 612, v = idx - g * 612;
        size_t b = (size_t)(b0 + g);
        float4 q = ((const float4*)(x + b * 2448))[v];
        ((float4*)(out + b * 2856))[v] = q; // out channels 0..71 = x
        float vv[4] = {q.x, q.y, q.z, q.w};
#pragma unroll
        for (int j = 0; j < 4; ++j) {
            int e = v * 4 + j;
            int cx = e / 34, h = e - cx * 34;
            const int ddv[6]  = {0, 36, 12, -12, -36, 0};
            const int sidx[6] = {0, 4, 3, 2, 1, 5};
            int rx = cx / 12;
            int cdst = cx + ddv[rx];
            float2 ab = AB[cdst];
            float s = gl[g][sidx[rx]];
            hp[g * 2592 + cdst * 36 + h + 1] = fmaxf(fmaf(ab.x * s, vv[j], ab.y), 0.f);
        }
    }
    __syncthreads();

    // conv: one thread per (batch, hh), 12 output-channel accumulators
    const float4* wT = (const float4*)(ws + WS_WT);
    for (int it = tid; it < nb * 34; it += 256) {
        int g = it / 34, hh = it - g * 34;
        const float* hb = &hp[g * 2592];
        float acc[12];
#pragma unroll
        for (int o = 0; o < 12; ++o) acc[o] = 0.f;
        for (int c = 0; c < 72; ++c) {
            float h0 = hb[c * 36 + hh];
            float h1 = hb[c * 36 + hh + 1];
            float h2 = hb[c * 36 + hh + 2];
#pragma unroll
            for (int o = 0; o < 12; ++o) {
                float4 wv = wT[c * 12 + o]; // uniform -> s_load_dwordx4
                acc[o] = fmaf(h0, wv.x, fmaf(h1, wv.y, fmaf(h2, wv.z, acc[o])));
            }
        }
        float* op = out + (size_t)(b0 + g) * 2856 + 2448;
#pragma unroll
        for (int o = 0; o < 12; ++o) op[o * 34 + hh] = acc[o];
    }
}

extern "C" void kernel_launch(void* const* d_in, const int* in_sizes, int n_in,
                              void* d_out, int out_size, void* d_ws, size_t ws_size,
                              hipStream_t stream)
{
    const float* x     = (const float*)d_in[0];
    const float* gamma = (const float*)d_in[1];
    const float* beta  = (const float*)d_in[2];
    const float* cw    = (const float*)d_in[3];
    const float* fw    = (const float*)d_in[4];
    const float* fb    = (const float*)d_in[5];
    float* out = (float*)d_out;
    float* ws  = (float*)d_ws;

    const int B = in_sizes[0] / (72 * 34);
    const int nTrip = (B + 2) / 3;

    // zero BN accumulators (ws is poisoned 0xAA before every call)
    hipMemsetAsync(ws, 0, 144 * sizeof(float), stream);

    k1_stats<<<1024, 256, 0, stream>>>(x, fw, fb, ws, B, nTrip);
    k2_finalize<<<1, 256, 0, stream>>>(gamma, beta, cw, ws, 1.f / ((float)B * 34.f));
    const int nb3 = (B + 5) / 6;
    k3_out<<<nb3, 256, 0, stream>>>(x, ws, out, B);
}

// Round 3
// 402.761 us; speedup vs baseline: 1.1668x; 1.1668x over previous
//
#include <hip/hip_runtime.h>
#include <hip/hip_fp16.h>
#include <math.h>

// B=16384, C=72, H=34, IN_CH=12, GROWTH=12, n=5
// out: (B, 84, 34) = concat([x, conv3x1(h)], ch)
// xxx channel map: region r=c/12, src = c + dd[r], dd={0,+36,+12,-12,-36,0}
// (involution). x channel cx feeds xxx channel cx+dd[cx/12] with gate index
// sidx[cx/12] = {0,4,3,2,1,5}. BN over xxx via gate-scaled per-batch row sums.

#define BN_EPS 1e-5f

// ws layout (float offsets)
#define WS_S    0      // 72
#define WS_SS   72     // 72
#define WS_A    144    // 72
#define WS_B    216    // 72
#define WS_WT   288    // 3456: conv_w as [c][o][4]
#define WS_GATE 3744   // B*6 gates; partials follow at WS_GATE + B*6
#define K1_BLOCKS 512

__device__ __forceinline__ float sigmoidf_(float z) { return 1.f / (1.f + expf(-z)); }

// ---------------------------------------------------------------------------
// K1: gates + per-block BN partial sums. thread=(g,c) reads 34 floats direct
// from global (17 float2; wave footprint 8.7KB stays L1-resident -> coalesced
// over the unrolled loop). No LDS staging. Partials out, no atomics.
// ---------------------------------------------------------------------------
__global__ __launch_bounds__(256) void k1_stats(const float* __restrict__ x,
                                                const float* __restrict__ fw,
                                                const float* __restrict__ fb,
                                                float* __restrict__ ws,
                                                float* __restrict__ part,
                                                int B, int nTrip)
{
    __shared__ float rs_s[3][72], rss_s[3][72], wsum_s[3][72];
    __shared__ float lm_s[3][6];
    __shared__ float sc_s[3][8];
    __shared__ float Sacc[144];

    const int tid = threadIdx.x;
    const int g = tid / 72;          // batch-in-trip (0..2 for tid<216)
    const int c = tid - g * 72;      // channel
    if (tid < 144) Sacc[tid] = 0.f;

    for (int t = blockIdx.x; t < nTrip; t += K1_BLOCKS) {
        const int b0 = t * 3;

        if (tid < 216 && b0 + g < B) {
            const float2* p = (const float2*)(x + (size_t)(b0 + g) * 2448 + c * 34);
            float rs = 0.f, rss = 0.f, wsm = 0.f;
#pragma unroll
            for (int i = 0; i < 17; ++i) {
                float2 v = p[i];
                rs += v.x + v.y;
                rss = fmaf(v.x, v.x, fmaf(v.y, v.y, rss));
                wsm = fmaf(v.x, fw[2 * i], fmaf(v.y, fw[2 * i + 1], wsm));
            }
            rs_s[g][c] = rs; rss_s[g][c] = rss; wsum_s[g][c] = wsm;
        }
        __syncthreads();

        // region sums -> lm (18 threads)
        if (tid < 18) {
            int gg = tid / 6, r = tid - gg * 6;
            float s = 0.f;
#pragma unroll
            for (int k = 0; k < 12; ++k) s += wsum_s[gg][r * 12 + k];
            lm_s[gg][r] = s * (1.f / 12.f) + fb[0];
        }
        __syncthreads();

        // gates (3 threads)
        if (tid < 3 && b0 + tid < B) {
            float lin_out = lm_s[tid][5];
            float sc[6];
            sc[0] = sigmoidf_(lin_out + lm_s[tid][0]);  // g1
            sc[1] = sigmoidf_(lm_s[tid][4] + lin_out);  // gates[3]
            sc[2] = sigmoidf_(lm_s[tid][3] + lin_out);  // gates[2]
            sc[3] = sigmoidf_(lm_s[tid][2] + lin_out);  // gates[1]
            sc[4] = sigmoidf_(lm_s[tid][1] + lin_out);  // gates[0]
            sc[5] = 1.f;
            float* gb = ws + WS_GATE + (size_t)(b0 + tid) * 6;
#pragma unroll
            for (int r = 0; r < 6; ++r) { sc_s[tid][r] = sc[r]; gb[r] = sc[r]; }
        }
        __syncthreads();

        // BN stat accumulation (72 threads), src permutation
        if (tid < 72) {
            const int r = tid / 12;
            const int dd[6] = {0, 36, 12, -12, -36, 0};
            const int src = tid + dd[r];
            float a = 0.f, q = 0.f;
#pragma unroll
            for (int gg = 0; gg < 3; ++gg) {
                if (b0 + gg < B) {
                    float s = sc_s[gg][r];
                    a = fmaf(s, rs_s[gg][src], a);
                    q = fmaf(s * s, rss_s[gg][src], q);
                }
            }
            Sacc[tid] += a; Sacc[72 + tid] += q;
        }
        __syncthreads();
    }

    if (tid < 144) part[(size_t)tid * K1_BLOCKS + blockIdx.x] = Sacc[tid];
}

// ---------------------------------------------------------------------------
// K2a: reduce partials (144 blocks, one per stat channel; coalesced reads)
// ---------------------------------------------------------------------------
__global__ __launch_bounds__(256) void k2a_reduce(float* __restrict__ ws,
                                                  const float* __restrict__ part)
{
    const int ch = blockIdx.x;
    const float* p = part + (size_t)ch * K1_BLOCKS;
    float s = 0.f;
    for (int i = threadIdx.x; i < K1_BLOCKS; i += 256) s += p[i];
#pragma unroll
    for (int off = 32; off; off >>= 1) s += __shfl_down(s, off, 64);
    __shared__ float wsum[4];
    if ((threadIdx.x & 63) == 0) wsum[threadIdx.x >> 6] = s;
    __syncthreads();
    if (threadIdx.x == 0) ws[WS_S + ch] = wsum[0] + wsum[1] + wsum[2] + wsum[3];
}

// ---------------------------------------------------------------------------
// K2b: finalize BN affine + transpose conv_w -> [c][o][4]
// ---------------------------------------------------------------------------
__global__ void k2b_finalize(const float* __restrict__ gamma,
                             const float* __restrict__ beta,
                             const float* __restrict__ cw,
                             float* __restrict__ ws, float invN)
{
    const int tid = threadIdx.x;
    if (tid < 72) {
        float S = ws[WS_S + tid], SS = ws[WS_SS + tid];
        float mu = S * invN;
        float var = SS * invN - mu * mu;
        float inv = rsqrtf(var + BN_EPS);
        float A = gamma[tid] * inv;
        ws[WS_A + tid] = A;
        ws[WS_B + tid] = beta[tid] - mu * A;
    }
    for (int i = tid; i < 12 * 72 * 3; i += 256) {
        int o = i / 216, rem = i - o * 216;
        int c = rem / 3, k = rem - c * 3;
        ws[WS_WT + c * 48 + o * 4 + k] = cw[i];
    }
}

// ---------------------------------------------------------------------------
// K3: transform + conv + output. 6 batches/block; h in LDS as fp16,
// per-batch stride 2456 halfs: [0..3]=zero pad, [4..2451]=h (channel rows
// contiguous, stride 34), [2452..2455]=zero pad. A float4 of x never
// straddles a region boundary (408 % 4 == 0), and the permutation only
// shifts whole regions, so 4 transformed values pack into ONE aligned
// 8B LDS write. Conv edges via loop-invariant masks.
// LDS ~30.3 KB -> 5 blocks/CU.
// ---------------------------------------------------------------------------
__global__ __launch_bounds__(256) void k3_out(const float* __restrict__ x,
                                              const float* __restrict__ ws,
                                              float* __restrict__ out, int B)
{
    __shared__ __align__(16) __half hs[6 * 2456];  // 29472 B
    __shared__ float2 AB[73];                      // [72] = padding entry
    __shared__ float gl[6][8];

    const int tid = threadIdx.x;
    const int b0 = blockIdx.x * 6;
    int nb = B - b0; if (nb > 6) nb = 6;

    if (tid < 73)
        AB[tid] = (tid < 72) ? make_float2(ws[WS_A + tid], ws[WS_B + tid])
                             : make_float2(0.f, 0.f);
    for (int t2 = tid; t2 < nb * 6; t2 += 256) {
        int g = t2 / 6, j = t2 - g * 6;
        gl[g][j] = ws[WS_GATE + (size_t)(b0 + g) * 6 + j];
    }
    // zero the 4-half pads (dwords {0,1,1226,1227} per batch region)
    if (tid < 24) {
        int g = tid >> 2, k = tid & 3;
        ((unsigned int*)hs)[g * 1228 + ((k < 2) ? k : (1224 + k))] = 0u;
    }
    __syncthreads();

    // transform: x float4 -> passthrough out + packed fp16 h into LDS
    for (int idx = tid; idx < nb * 612; idx += 256) {
        int g = idx / 612, v4 = idx - g * 612;
        size_t b = (size_t)(b0 + g);
        float4 q = ((const float4*)(x + b * 2448))[v4];
        ((float4*)(out + b * 2856))[v4] = q;

        const int ddc[6]  = {0, 36, 12, -12, -36, 0};
        const int sidx[6] = {0, 4, 3, 2, 1, 5};
        int rx = v4 / 102;              // region (uniform over the float4)
        int e  = v4 * 4;
        int cx0 = e / 34;
        int h0i = e - cx0 * 34;         // h of element 0 (0..33)
        int dd  = ddc[rx];
        int cd0 = cx0 + dd;
        float2 ab0 = AB[cd0];
        float2 ab1 = AB[cd0 + 1];
        float s = gl[g][sidx[rx]];
        float vv[4] = {q.x, q.y, q.z, q.w};
        __half hv[4];
#pragma unroll
        for (int j = 0; j < 4; ++j) {
            float2 ab = (h0i + j >= 34) ? ab1 : ab0;
            hv[j] = __float2half(fmaxf(fmaf(ab.x * s, vv[j], ab.y), 0.f));
        }
        union { __half2 h2; unsigned int u; } pa, pb;
        pa.h2 = __halves2half2(hv[0], hv[1]);
        pb.h2 = __halves2half2(hv[2], hv[3]);
        int dst = g * 2456 + 4 + e + dd * 34;      // multiple of 4 halfs
        *reinterpret_cast<uint2*>(&hs[dst]) = make_uint2(pa.u, pb.u);
    }
    __syncthreads();

    // conv: thread = (batch, hh); weights via uniform s_load; h reads are
    // consecutive halfs across lanes (2 lanes/bank = free)
    const float4* wT = (const float4*)(ws + WS_WT);
    for (int it = tid; it < nb * 34; it += 256) {
        int g = it / 34, hh = it - g * 34;
        const __half* hb = &hs[g * 2456 + 4 + hh];
        float m0 = (hh == 0) ? 0.f : 1.f;
        float m2 = (hh == 33) ? 0.f : 1.f;
        float acc[12];
#pragma unroll
        for (int o = 0; o < 12; ++o) acc[o] = 0.f;
        for (int c = 0; c < 72; ++c) {
            float h0 = m0 * __half2float(hb[c * 34 - 1]);
            float h1 =      __half2float(hb[c * 34]);
            float h2 = m2 * __half2float(hb[c * 34 + 1]);
#pragma unroll
            for (int o = 0; o < 12; ++o) {
                float4 wv = wT[c * 12 + o];
                acc[o] = fmaf(h0, wv.x, fmaf(h1, wv.y, fmaf(h2, wv.z, acc[o])));
            }
        }
        float* op = out + (size_t)(b0 + g) * 2856 + 2448;
#pragma unroll
        for (int o = 0; o < 12; ++o) op[o * 34 + hh] = acc[o];
    }
}

extern "C" void kernel_launch(void* const* d_in, const int* in_sizes, int n_in,
                              void* d_out, int out_size, void* d_ws, size_t ws_size,
                              hipStream_t stream)
{
    const float* x     = (const float*)d_in[0];
    const float* gamma = (const float*)d_in[1];
    const float* beta  = (const float*)d_in[2];
    const float* cw    = (const float*)d_in[3];
    const float* fw    = (const float*)d_in[4];
    const float* fb    = (const float*)d_in[5];
    float* out = (float*)d_out;
    float* ws  = (float*)d_ws;

    const int B = in_sizes[0] / (72 * 34);
    const int nTrip = (B + 2) / 3;
    float* part = ws + WS_GATE + (size_t)B * 6;   // 144*K1_BLOCKS floats

    k1_stats<<<K1_BLOCKS, 256, 0, stream>>>(x, fw, fb, ws, part, B, nTrip);
    k2a_reduce<<<144, 256, 0, stream>>>(ws, part);
    k2b_finalize<<<1, 256, 0, stream>>>(gamma, beta, cw, ws, 1.f / ((float)B * 34.f));
    k3_out<<<(B + 5) / 6, 256, 0, stream>>>(x, ws, out, B);
}